// Round 4
// baseline (284.652 us; speedup 1.0000x reference)
//
#include <hip/hip_runtime.h>

#define TSTEPS 15
#define HID    64
#define LAT    16
#define NBATCH 65536
#define LOG2E  1.44269504088896f
#define SSTR   74   // state row stride (fp16 elems). 74 => byte stride 148,
                    // bank = 5c mod 32: injective over c=0..15 (72 gave 4c
                    // mod 32 -> c / c+8 collide on EVERY state op; measured
                    // 2.95M conflict-cycles/dispatch, invariant across wave
                    // structures r0/r1 => state ops are the conflict source).

typedef _Float16 v8h __attribute__((ext_vector_type(8)));
typedef _Float16 v4h __attribute__((ext_vector_type(4)));
typedef _Float16 v2h __attribute__((ext_vector_type(2)));
typedef float    v4f __attribute__((ext_vector_type(4)));

__device__ __forceinline__ v8h vzero8() {
    v8h v;
#pragma unroll
    for (int i = 0; i < 8; ++i) v[i] = (_Float16)0.0f;
    return v;
}

// v_cvt_pkrtz returns __fp16x2; bit-cast to our _Float16x2 (same bits).
__device__ __forceinline__ v4h pack4(float a, float b, float c, float d) {
    const v2h lo = __builtin_bit_cast(v2h, __builtin_amdgcn_cvt_pkrtz(a, b));
    const v2h hi = __builtin_bit_cast(v2h, __builtin_amdgcn_cvt_pkrtz(c, d));
    return __builtin_shufflevector(lo, hi, 0, 1, 2, 3);
}

// LSTM cell update, shared-rcp merged form. Gate pre-acts arrive PRE-SCALED:
// i/f/o rows by log2e, g rows by 2*log2e (all folded into staged weights &
// biases), so every exp2 needs no multiply (neg is a free src modifier).
//   c' = [c*(1+ei)(1+eg) + (1-eg)(1+ef)] * rcp((1+ef)(1+ei)(1+eg))
//   h  = o*tanh(c') = (1-ec)*rcp((1+eo)(1+ec)), ec = exp2(-2c'*log2e)
// 5 exp2 + 2 rcp per unit. Verified by r3/r16 absmax (0.000488, passing).
__device__ __forceinline__ float cell_update(float ai, float af, float ag,
                                             float ao, float& cst) {
    const float ei = __builtin_amdgcn_exp2f(-ai);
    const float ef = __builtin_amdgcn_exp2f(-af);
    const float eg = __builtin_amdgcn_exp2f(-ag);   // ag pre-scaled by 2log2e
    const float eo = __builtin_amdgcn_exp2f(-ao);
    const float p1  = (1.0f + ei) * (1.0f + eg);
    const float pf  = 1.0f + ef;
    const float num = fmaf(cst, p1, (1.0f - eg) * pf);
    const float cc  = num * __builtin_amdgcn_rcpf(p1 * pf);
    cst = cc;
    const float ec = __builtin_amdgcn_exp2f(cc * (-2.0f * LOG2E));  // true scale
    return (1.0f - ec) *
        __builtin_amdgcn_rcpf((1.0f + eo) * (1.0f + ec));      // o*tanh(c)
}

// Round 17: latency-exposure pass on the 16-wave structure.
// MODEL (r0-r3 evidence): no pipe saturated (VALU 54%, LDS ~45%, MFMA-issue
// ~3%); latency-bound on the recurrence. TLP hard-capped at 4 waves/SIMD
// (1024-thr block cap + 1-block-LDS + full 128-reg budget). Any A-reuse
// scheme needs >=2 batch-groups/wave => +16-64 regs => spill (r1/r2 proved).
// So: kill exposed latency + the measured bank conflicts.
//  (a) SSTR 72->74: conflict-free state ops (see #define).
//  (b) loop rotation: FC(tt-2) issued after the clobber + l0_part(tt), so
//      the gf reload->FC chain (~300 cyc, previously trapped at iteration
//      end by the clobber) hides under 48 MFMAs.
//  (c) setprio dropped (r3 vs r0: +1us with less work => mild suspect).
// Kept: merged-rcp cell_update, g-rows staged at 2*LOG2E (both verified).
// DO NOT RE-ATTEMPT: xp-hoist (r2 spill: needs 64 regs/lane), 8-wave/
// 32-batch A-reuse (r1: latency-bound regression), >4 waves/EU (registers).
//
// LOAD-BEARING (round 7): without the per-iteration asm memory clobber,
// LICM/CSE keeps all A-fragment ds_reads (448 VGPRs worth) live across
// t-iterations -> forced scratch spill -> GBs of HBM scratch traffic.
// DO NOT REMOVE. Clobbers are also required between PEELED sections that
// re-read the same planes (t=0/t=1 peel, epilogue).
//
//   D[m=gate(256), n=batch(16)] = A[weights*scale] * B[z | h0 | x | h1]
// wf planes: 0=Wih0(z,K16; k=16 -> bias; rest 0) 1,2=Whh0 3,4=Wih1 5,6=Whh1.
// Gate order (PyTorch): 0=i,1=f,2=g,3=o ; g = 64*type + u, u=16a+4q+r;
// acc[ty] -> ty IS the gate type (mt = 4*ty+a).
__global__ __launch_bounds__(1024)
__attribute__((amdgpu_waves_per_eu(4, 4)))
void lstm2_pipe8(
        const float* __restrict__ z,
        const float* __restrict__ Wih0, const float* __restrict__ Whh0,
        const float* __restrict__ bih0, const float* __restrict__ bhh0,
        const float* __restrict__ Wih1, const float* __restrict__ Whh1,
        const float* __restrict__ bih1, const float* __restrict__ bhh1,
        const float* __restrict__ Wfc,  const float* __restrict__ bfc,
        float* __restrict__ out)
{
    __shared__ __align__(16) _Float16 wf[7 * 16 * 64 * 8];    // 114688 B
    __shared__ __align__(16) _Float16 wfcf[2 * 64 * 8];       //   2048 B
    __shared__ __align__(16) float    bsum1[256];             //   1024 B
    __shared__ __align__(16) _Float16 state[16][16 * SSTR];   //  37888 B
                                                              // 155648 B total

    const int tid  = threadIdx.x;
    const int wave = tid >> 6;           // 0..15
    const int lane = tid & 63;
    const int q    = lane >> 4;          // quad
    const int c    = lane & 15;          // batch col
    const int row0 = blockIdx.x * 256 + wave * 16;   // wave's batch base

    /* --- one-time staging: weights + biases, scaled (g rows by 2log2e) --- */
#pragma unroll 2
    for (int e = tid; e < 7 * 16 * 64 * 8; e += 1024) {
        const int j  = e & 7;
        const int lm = (e >> 3) & 63;
        const int mt = (e >> 9) & 15;
        const int p  = e >> 13;                  // fragment plane 0..6
        const int g  = mt * 16 + (lm & 15);      // gate row 0..255
        const int kk = (lm >> 4) * 8 + j;        // k within 32-chunk
        float v;
        if (p == 0)      v = (kk < LAT) ? Wih0[g * LAT + kk]
                           : (kk == LAT ? bih0[g] + bhh0[g] : 0.0f);
        else if (p == 1) v = Whh0[g * HID + kk];
        else if (p == 2) v = Whh0[g * HID + 32 + kk];
        else if (p == 3) v = Wih1[g * HID + kk];
        else if (p == 4) v = Wih1[g * HID + 32 + kk];
        else if (p == 5) v = Whh1[g * HID + kk];
        else             v = Whh1[g * HID + 32 + kk];
        const float sc = ((g >> 6) == 2) ? (2.0f * LOG2E) : LOG2E;
        wf[e] = (_Float16)(v * sc);
    }
    // FC A-fragments: row m=0 carries Wfc (TRUE scale), rows 1..15 zero
    if (tid < 2 * 64 * 8) {
        const int e  = tid;
        const int j  = e & 7;
        const int lm = (e >> 3) & 63;
        const int kc = e >> 9;
        const int kk = kc * 32 + (lm >> 4) * 8 + j;
        wfcf[e] = ((lm & 15) == 0) ? (_Float16)Wfc[kk] : (_Float16)0.0f;
    }
    if (tid < 256)
        bsum1[tid] = (bih1[tid] + bhh1[tid]) *
                     (((tid >> 6) == 2) ? (2.0f * LOG2E) : LOG2E);
    __syncthreads();   // the only barrier in the kernel

    _Float16* stW = &state[wave][0];
    const float bfcv = bfc[0];

    // FC fragments hoisted (SSA regs survive the clobber)
    const v8h wfc0 = *(const v8h*)&wfcf[(0 * 64 + lane) * 8];
    const v8h wfc1 = *(const v8h*)&wfcf[(1 * 64 + lane) * 8];

    // z B-fragment (constant over t); element k=16 = 1.0 multiplies the
    // (scaled) bias column staged in plane 0.
    v8h zfrag = vzero8();
    if (q < 2) {
        const float* zp = z + (size_t)(row0 + c) * LAT + q * 8;
        const float4 za = *(const float4*)(zp);
        const float4 zb = *(const float4*)(zp + 4);
        zfrag[0] = (_Float16)za.x; zfrag[1] = (_Float16)za.y;
        zfrag[2] = (_Float16)za.z; zfrag[3] = (_Float16)za.w;
        zfrag[4] = (_Float16)zb.x; zfrag[5] = (_Float16)zb.y;
        zfrag[6] = (_Float16)zb.z; zfrag[7] = (_Float16)zb.w;
    }
    if (q == 2) zfrag[0] = (_Float16)1.0f;   // bias slot

    v8h hf0 = vzero8(), hf1 = vzero8();   // h0/x B-frags (k-halves)
    v8h gf0 = vzero8(), gf1 = vzero8();   // h1 B-frags
    v4h h1pk[4];                          // packed h1 awaiting deferred write
    float c0s[16], c1s[16];
#pragma unroll
    for (int i = 0; i < 16; ++i) { c0s[i] = 0.0f; c1s[i] = 0.0f; }

#define AFRAG(pl, mt) (*(const v8h*)&wf[(((pl) * 16 + (mt)) * 64 + lane) * 8])
#define MFMA16(A, B, C) __builtin_amdgcn_mfma_f32_16x16x32_f16((A), (B), (C), 0, 0, 0)

    auto l0_part = [&]() {   // L0 MFMAs + epilogue + h0 stores (uses old hf)
#pragma unroll
        for (int a = 0; a < 4; ++a) {
            v4f acc0[4];
#pragma unroll
            for (int ty = 0; ty < 4; ++ty) {
                const int mt = 4 * ty + a;
                v4f t0 = {0.f, 0.f, 0.f, 0.f};
                t0 = MFMA16(AFRAG(0, mt), zfrag, t0);
                t0 = MFMA16(AFRAG(1, mt), hf0,   t0);
                t0 = MFMA16(AFRAG(2, mt), hf1,   t0);
                acc0[ty] = t0;
            }
            float hh[4];
#pragma unroll
            for (int r = 0; r < 4; ++r)
                hh[r] = cell_update(acc0[0][r], acc0[1][r], acc0[2][r],
                                    acc0[3][r], c0s[a * 4 + r]);
            *(v4h*)&stW[c * SSTR + 16 * a + 4 * q] =
                pack4(hh[0], hh[1], hh[2], hh[3]);
        }
    };

    auto l1_part = [&]() {   // L1 MFMAs + epilogue -> h1pk (uses old hf, gf)
#pragma unroll
        for (int a = 0; a < 4; ++a) {
            v4f acc1[4];
#pragma unroll
            for (int ty = 0; ty < 4; ++ty) {
                const int mt = 4 * ty + a;
                v4f t0 = *(const v4f*)&bsum1[64 * ty + 16 * a + 4 * q];
                t0 = MFMA16(AFRAG(3, mt), hf0, t0);
                t0 = MFMA16(AFRAG(4, mt), hf1, t0);
                t0 = MFMA16(AFRAG(5, mt), gf0, t0);
                t0 = MFMA16(AFRAG(6, mt), gf1, t0);
                acc1[ty] = t0;
            }
            float hh[4];
#pragma unroll
            for (int r = 0; r < 4; ++r)
                hh[r] = cell_update(acc1[0][r], acc1[1][r], acc1[2][r],
                                    acc1[3][r], c1s[a * 4 + r]);
            h1pk[a] = pack4(hh[0], hh[1], hh[2], hh[3]);
        }
    };

    auto l0_finish = [&]() {   // pull new h0 into B-frag registers
        hf0 = *(const v8h*)&stW[c * SSTR + 8 * q];
        hf1 = *(const v8h*)&stW[c * SSTR + 32 + 8 * q];
    };

    auto l1_store_gf = [&]() {   // h1 store + gf reload (FC deferred)
#pragma unroll
        for (int a = 0; a < 4; ++a)
            *(v4h*)&stW[c * SSTR + 16 * a + 4 * q] = h1pk[a];
        gf0 = *(const v8h*)&stW[c * SSTR + 8 * q];
        gf1 = *(const v8h*)&stW[c * SSTR + 32 + 8 * q];
    };

    auto fc_out = [&](int trow) {   // FC on current gf, write out row
        v4f f = {0.f, 0.f, 0.f, 0.f};
        f = MFMA16(wfc0, gf0, f);
        f = MFMA16(wfc1, gf1, f);
        if (lane < 16)
            out[(size_t)(row0 + lane) * TSTEPS + trow] = f[0] + bfcv;
    };

    /* --------------------------- pipeline ---------------------------
       Rotated: FC for step tt-2 runs at the TOP of iteration tt (after
       the clobber + l0_part), so the gf reload issued at the end of the
       previous iteration has its latency hidden under 48 MFMAs.       */
    l0_part();          // L0 step 0 (hf, gf are zero)
    l0_finish();

    __asm__ __volatile__("" ::: "memory");   // bars A-frag CSE across peels
    l0_part();          // L0 step 1
    l1_part();          // L1 step 0 -> h1pk
    l0_finish();        // hf <- h0(1)
    l1_store_gf();      // gf <- h1(0)

#pragma unroll 1
    for (int tt = 2; tt < TSTEPS; ++tt) {
        // Kill LICM/CSE (see header comment). Emits no instructions.
        __asm__ __volatile__("" ::: "memory");
        l0_part();           // writes h0(tt) to stW
        fc_out(tt - 2);      // FC(h1(tt-2)); gf-read latency already covered
        l1_part();           // -> h1pk = h1(tt-1); uses gf = h1(tt-2)
        l0_finish();         // hf <- h0(tt)
        l1_store_gf();       // gf <- h1(tt-1)
    }

    __asm__ __volatile__("" ::: "memory");
    l1_part();               // L1 step 14 (gf = h1(13))
    fc_out(TSTEPS - 2);      // FC(h1(13)) before gf is overwritten
    l1_store_gf();           // gf <- h1(14)
    fc_out(TSTEPS - 1);

#undef AFRAG
#undef MFMA16
}

extern "C" void kernel_launch(void* const* d_in, const int* in_sizes, int n_in,
                              void* d_out, int out_size, void* d_ws, size_t ws_size,
                              hipStream_t stream)
{
    (void)in_sizes; (void)n_in; (void)out_size; (void)d_ws; (void)ws_size;

    const float* z    = (const float*)d_in[0];
    const float* Wih0 = (const float*)d_in[1];
    const float* Whh0 = (const float*)d_in[2];
    const float* bih0 = (const float*)d_in[3];
    const float* bhh0 = (const float*)d_in[4];
    const float* Wih1 = (const float*)d_in[5];
    const float* Whh1 = (const float*)d_in[6];
    const float* bih1 = (const float*)d_in[7];
    const float* bhh1 = (const float*)d_in[8];
    const float* Wfc  = (const float*)d_in[9];
    const float* bfc  = (const float*)d_in[10];

    lstm2_pipe8<<<dim3(NBATCH / 256), dim3(1024), 0, stream>>>(
        z, Wih0, Whh0, bih0, bhh0, Wih1, Whh1, bih1, bhh1, Wfc, bfc,
        (float*)d_out);
}

// Round 5
// 250.422 us; speedup vs baseline: 1.1367x; 1.1367x over previous
//
#include <hip/hip_runtime.h>

#define TSTEPS 15
#define HID    64
#define LAT    16
#define NBATCH 65536
#define LOG2E  1.44269504088896f

typedef _Float16 v8h __attribute__((ext_vector_type(8)));
typedef _Float16 v4h __attribute__((ext_vector_type(4)));
typedef _Float16 v2h __attribute__((ext_vector_type(2)));
typedef float    v4f __attribute__((ext_vector_type(4)));

__device__ __forceinline__ v8h vzero8() {
    v8h v;
#pragma unroll
    for (int i = 0; i < 8; ++i) v[i] = (_Float16)0.0f;
    return v;
}

// v_cvt_pkrtz returns __fp16x2; bit-cast to our _Float16x2 (same bits).
__device__ __forceinline__ v4h pack4(float a, float b, float c, float d) {
    const v2h lo = __builtin_bit_cast(v2h, __builtin_amdgcn_cvt_pkrtz(a, b));
    const v2h hi = __builtin_bit_cast(v2h, __builtin_amdgcn_cvt_pkrtz(c, d));
    return __builtin_shufflevector(lo, hi, 0, 1, 2, 3);
}

// LSTM cell update, shared-rcp merged form. Gate pre-acts arrive PRE-SCALED:
// i/f/o rows by log2e, g rows by 2*log2e (all folded into staged weights &
// biases), so every exp2 needs no multiply (neg is a free src modifier).
//   c' = [c*(1+ei)(1+eg) + (1-eg)(1+ef)] * rcp((1+ef)(1+ei)(1+eg))
//   h  = o*tanh(c') = (1-ec)*rcp((1+eo)(1+ec)), ec = exp2(-2c'*log2e)
// 5 exp2 + 2 rcp per unit. Numerics verified (r3: absmax 0.000488, passing).
__device__ __forceinline__ float cell_update(float ai, float af, float ag,
                                             float ao, float& cst) {
    const float ei = __builtin_amdgcn_exp2f(-ai);
    const float ef = __builtin_amdgcn_exp2f(-af);
    const float eg = __builtin_amdgcn_exp2f(-ag);   // ag pre-scaled by 2log2e
    const float eo = __builtin_amdgcn_exp2f(-ao);
    const float p1  = (1.0f + ei) * (1.0f + eg);
    const float pf  = 1.0f + ef;
    const float num = fmaf(cst, p1, (1.0f - eg) * pf);
    const float cc  = num * __builtin_amdgcn_rcpf(p1 * pf);
    cst = cc;
    const float ec = __builtin_amdgcn_exp2f(cc * (-2.0f * LOG2E));  // true scale
    return (1.0f - ec) *
        __builtin_amdgcn_rcpf((1.0f + eo) * (1.0f + ec));      // o*tanh(c)
}

// Round 18: revert to best-known structure (r0/r3, ~205 us steady), ablating
// setprio (the one never-isolated r0<->r3 delta; weak evidence it costs ~1us).
//
// STRUCTURAL MODEL (rounds 0-4, all measured):
//  - No pipe saturated: VALU 54%, LDS ~50%, MFMA-pipe 27%. Latency-bound
//    recurrence with TLP hard-capped at 4 waves/SIMD by THREE independent
//    walls: 1024-thr block max, 154 KB LDS => 1 block/CU, and the 128-reg/
//    wave budget fully used (64 VGPR + 64 AGPR).
//  - DO NOT RE-ATTEMPT (each regressed or spilled, with counters):
//    r1: 8-wave/32-batch A-frag reuse -> 218 us (latency-bound at 2 w/SIMD;
//        NOT LDS-BW-bound).
//    r2: xp-hoist -> 64 f32/lane -> scratch spill (FETCH 3.5->92 MB).
//    r3: VALU diet (kept here) -> neutral: VALU is not the critical path.
//    r4: SSTR=74 conflict fix -> broke 16B alignment, regressed; conflicts
//        were only 2.3% of cycles (2-way = near-free per m136) and are
//        STRUCTURAL with aligned b128 state ops. Loop rotation also in the
//        regression mix. Leave both alone.
//    32x32 MFMA shape / 6 waves-per-EU / batch-pairing: all need registers
//    that don't exist (>= 85-reg cap at 6 w/EU vs ~128 live).
//
// LOAD-BEARING (round 7): without the per-iteration asm memory clobber,
// LICM/CSE keeps all A-fragment ds_reads (448 VGPRs worth) live across
// t-iterations -> forced scratch spill -> GBs of HBM scratch traffic.
// DO NOT REMOVE. (Pre-loop register loads are SSA values, survive it.)
//
// Merged steady-state body (one BB): L0(tt) + L1(tt-1). Per-wave LDS
// state machine: write h0(tt) -> read hf -> write h1(tt-1) -> read gf -> FC.
//
//   D[m=gate(256), n=batch(16)] = A[weights*scale] * B[z | h0 | x | h1]
// wf planes: 0=Wih0(z,K16; k=16 -> bias; rest 0) 1,2=Whh0 3,4=Wih1 5,6=Whh1.
// Gate order (PyTorch): 0=i,1=f,2=g,3=o ; g = 64*type + u, u=16a+4q+r;
// acc[ty] -> ty IS the gate type (mt = 4*ty+a).
__global__ __launch_bounds__(1024)
__attribute__((amdgpu_waves_per_eu(4, 4)))
void lstm2_pipe9(
        const float* __restrict__ z,
        const float* __restrict__ Wih0, const float* __restrict__ Whh0,
        const float* __restrict__ bih0, const float* __restrict__ bhh0,
        const float* __restrict__ Wih1, const float* __restrict__ Whh1,
        const float* __restrict__ bih1, const float* __restrict__ bhh1,
        const float* __restrict__ Wfc,  const float* __restrict__ bfc,
        float* __restrict__ out)
{
    __shared__ __align__(16) _Float16 wf[7 * 16 * 64 * 8];   // 114688 B
    __shared__ __align__(16) _Float16 wfcf[2 * 64 * 8];      //   2048 B
    __shared__ __align__(16) float    bsum1[256];            //   1024 B
    __shared__ __align__(16) _Float16 state[16][16 * 72];    //  36864 B
                                                             // 154624 B total

    const int tid  = threadIdx.x;
    const int wave = tid >> 6;           // 0..15
    const int lane = tid & 63;
    const int q    = lane >> 4;          // quad
    const int c    = lane & 15;          // batch col
    const int row0 = blockIdx.x * 256 + wave * 16;   // wave's batch base

    /* --- one-time staging: weights + biases, scaled (g rows by 2log2e) --- */
#pragma unroll 2
    for (int e = tid; e < 7 * 16 * 64 * 8; e += 1024) {
        const int j  = e & 7;
        const int lm = (e >> 3) & 63;
        const int mt = (e >> 9) & 15;
        const int p  = e >> 13;                  // fragment plane 0..6
        const int g  = mt * 16 + (lm & 15);      // gate row 0..255
        const int kk = (lm >> 4) * 8 + j;        // k within 32-chunk
        float v;
        if (p == 0)      v = (kk < LAT) ? Wih0[g * LAT + kk]
                           : (kk == LAT ? bih0[g] + bhh0[g] : 0.0f);
        else if (p == 1) v = Whh0[g * HID + kk];
        else if (p == 2) v = Whh0[g * HID + 32 + kk];
        else if (p == 3) v = Wih1[g * HID + kk];
        else if (p == 4) v = Wih1[g * HID + 32 + kk];
        else if (p == 5) v = Whh1[g * HID + kk];
        else             v = Whh1[g * HID + 32 + kk];
        const float sc = ((g >> 6) == 2) ? (2.0f * LOG2E) : LOG2E;
        wf[e] = (_Float16)(v * sc);
    }
    // FC A-fragments: row m=0 carries Wfc (TRUE scale), rows 1..15 zero
    if (tid < 2 * 64 * 8) {
        const int e  = tid;
        const int j  = e & 7;
        const int lm = (e >> 3) & 63;
        const int kc = e >> 9;
        const int kk = kc * 32 + (lm >> 4) * 8 + j;
        wfcf[e] = ((lm & 15) == 0) ? (_Float16)Wfc[kk] : (_Float16)0.0f;
    }
    if (tid < 256)
        bsum1[tid] = (bih1[tid] + bhh1[tid]) *
                     (((tid >> 6) == 2) ? (2.0f * LOG2E) : LOG2E);
    __syncthreads();   // the only barrier in the kernel

    _Float16* stW = &state[wave][0];
    const float bfcv = bfc[0];

    // FC fragments hoisted (SSA regs survive the clobber)
    const v8h wfc0 = *(const v8h*)&wfcf[(0 * 64 + lane) * 8];
    const v8h wfc1 = *(const v8h*)&wfcf[(1 * 64 + lane) * 8];

    // z B-fragment (constant over t); element k=16 = 1.0 multiplies the
    // (scaled) bias column staged in plane 0.
    v8h zfrag = vzero8();
    if (q < 2) {
        const float* zp = z + (size_t)(row0 + c) * LAT + q * 8;
        const float4 za = *(const float4*)(zp);
        const float4 zb = *(const float4*)(zp + 4);
        zfrag[0] = (_Float16)za.x; zfrag[1] = (_Float16)za.y;
        zfrag[2] = (_Float16)za.z; zfrag[3] = (_Float16)za.w;
        zfrag[4] = (_Float16)zb.x; zfrag[5] = (_Float16)zb.y;
        zfrag[6] = (_Float16)zb.z; zfrag[7] = (_Float16)zb.w;
    }
    if (q == 2) zfrag[0] = (_Float16)1.0f;   // bias slot

    v8h hf0 = vzero8(), hf1 = vzero8();   // h0/x B-frags (k-halves)
    v8h gf0 = vzero8(), gf1 = vzero8();   // h1 B-frags
    v4h h1pk[4];                          // packed h1 awaiting deferred write
    float c0s[16], c1s[16];
#pragma unroll
    for (int i = 0; i < 16; ++i) { c0s[i] = 0.0f; c1s[i] = 0.0f; }

#define AFRAG(pl, mt) (*(const v8h*)&wf[(((pl) * 16 + (mt)) * 64 + lane) * 8])
#define MFMA16(A, B, C) __builtin_amdgcn_mfma_f32_16x16x32_f16((A), (B), (C), 0, 0, 0)

    auto l0_part = [&]() {   // L0 MFMAs + epilogue + h0 stores (uses old hf)
#pragma unroll
        for (int a = 0; a < 4; ++a) {
            v4f acc0[4];
#pragma unroll
            for (int ty = 0; ty < 4; ++ty) {
                const int mt = 4 * ty + a;
                v4f t0 = {0.f, 0.f, 0.f, 0.f};
                t0 = MFMA16(AFRAG(0, mt), zfrag, t0);
                t0 = MFMA16(AFRAG(1, mt), hf0,   t0);
                t0 = MFMA16(AFRAG(2, mt), hf1,   t0);
                acc0[ty] = t0;
            }
            float hh[4];
#pragma unroll
            for (int r = 0; r < 4; ++r)
                hh[r] = cell_update(acc0[0][r], acc0[1][r], acc0[2][r],
                                    acc0[3][r], c0s[a * 4 + r]);
            *(v4h*)&stW[c * 72 + 16 * a + 4 * q] = pack4(hh[0], hh[1], hh[2], hh[3]);
        }
    };

    auto l1_part = [&]() {   // L1 MFMAs + epilogue -> h1pk (uses old hf, gf)
#pragma unroll
        for (int a = 0; a < 4; ++a) {
            v4f acc1[4];
#pragma unroll
            for (int ty = 0; ty < 4; ++ty) {
                const int mt = 4 * ty + a;
                v4f t0 = *(const v4f*)&bsum1[64 * ty + 16 * a + 4 * q];
                t0 = MFMA16(AFRAG(3, mt), hf0, t0);
                t0 = MFMA16(AFRAG(4, mt), hf1, t0);
                t0 = MFMA16(AFRAG(5, mt), gf0, t0);
                t0 = MFMA16(AFRAG(6, mt), gf1, t0);
                acc1[ty] = t0;
            }
            float hh[4];
#pragma unroll
            for (int r = 0; r < 4; ++r)
                hh[r] = cell_update(acc1[0][r], acc1[1][r], acc1[2][r],
                                    acc1[3][r], c1s[a * 4 + r]);
            h1pk[a] = pack4(hh[0], hh[1], hh[2], hh[3]);
        }
    };

    auto l0_finish = [&]() {   // pull new h0 into B-frag registers
        hf0 = *(const v8h*)&stW[c * 72 + 8 * q];
        hf1 = *(const v8h*)&stW[c * 72 + 32 + 8 * q];
    };

    auto l1_finish = [&](int trow) {   // h1 store, gf reload, FC, out
#pragma unroll
        for (int a = 0; a < 4; ++a)
            *(v4h*)&stW[c * 72 + 16 * a + 4 * q] = h1pk[a];
        gf0 = *(const v8h*)&stW[c * 72 + 8 * q];
        gf1 = *(const v8h*)&stW[c * 72 + 32 + 8 * q];
        v4f f = {0.f, 0.f, 0.f, 0.f};
        f = MFMA16(wfc0, gf0, f);
        f = MFMA16(wfc1, gf1, f);
        if (lane < 16)
            out[(size_t)(row0 + lane) * TSTEPS + trow] = f[0] + bfcv;
    };

    /* --------------------------- pipeline --------------------------- */
    l0_part();          // L0 step 0 (hf, gf are zero)
    l0_finish();

#pragma unroll 1
    for (int tt = 1; tt < TSTEPS; ++tt) {
        // Kill LICM (see header comment). Emits no instructions.
        __asm__ __volatile__("" ::: "memory");
        l0_part();           // writes h0(tt) to stW
        l1_part();           // -> h1pk (registers only)
        l0_finish();         // hf <- h0(tt)
        l1_finish(tt - 1);   // h1 store, gf <- h1(tt-1), FC, out row tt-1
    }

    __asm__ __volatile__("" ::: "memory");
    l1_part();          // L1 step 14
    l1_finish(TSTEPS - 1);

#undef AFRAG
#undef MFMA16
}

extern "C" void kernel_launch(void* const* d_in, const int* in_sizes, int n_in,
                              void* d_out, int out_size, void* d_ws, size_t ws_size,
                              hipStream_t stream)
{
    (void)in_sizes; (void)n_in; (void)out_size; (void)d_ws; (void)ws_size;

    const float* z    = (const float*)d_in[0];
    const float* Wih0 = (const float*)d_in[1];
    const float* Whh0 = (const float*)d_in[2];
    const float* bih0 = (const float*)d_in[3];
    const float* bhh0 = (const float*)d_in[4];
    const float* Wih1 = (const float*)d_in[5];
    const float* Whh1 = (const float*)d_in[6];
    const float* bih1 = (const float*)d_in[7];
    const float* bhh1 = (const float*)d_in[8];
    const float* Wfc  = (const float*)d_in[9];
    const float* bfc  = (const float*)d_in[10];

    lstm2_pipe9<<<dim3(NBATCH / 256), dim3(1024), 0, stream>>>(
        z, Wih0, Whh0, bih0, bhh0, Wih1, Whh1, bih1, bhh1, Wfc, bfc,
        (float*)d_out);
}

// Round 6
// 242.909 us; speedup vs baseline: 1.1718x; 1.0309x over previous
//
#include <hip/hip_runtime.h>

#define TSTEPS 15
#define HID    64
#define LAT    16
#define NBATCH 65536
#define LOG2E  1.44269504088896f

typedef _Float16 v8h __attribute__((ext_vector_type(8)));
typedef _Float16 v4h __attribute__((ext_vector_type(4)));
typedef _Float16 v2h __attribute__((ext_vector_type(2)));
typedef float    v4f __attribute__((ext_vector_type(4)));

__device__ __forceinline__ v8h vzero8() {
    v8h v;
#pragma unroll
    for (int i = 0; i < 8; ++i) v[i] = (_Float16)0.0f;
    return v;
}

// v_cvt_pkrtz returns __fp16x2; bit-cast to our _Float16x2 (same bits).
__device__ __forceinline__ v4h pack4(float a, float b, float c, float d) {
    const v2h lo = __builtin_bit_cast(v2h, __builtin_amdgcn_cvt_pkrtz(a, b));
    const v2h hi = __builtin_bit_cast(v2h, __builtin_amdgcn_cvt_pkrtz(c, d));
    return __builtin_shufflevector(lo, hi, 0, 1, 2, 3);
}

// LSTM cell update, shared-rcp merged form. Gate pre-acts arrive PRE-SCALED:
// i/f/o rows by log2e, g rows by 2*log2e (all folded into staged weights &
// biases), so every exp2 needs no multiply (neg is a free src modifier).
//   c' = [c*(1+ei)(1+eg) + (1-eg)(1+ef)] * rcp((1+ef)(1+ei)(1+eg))
//   h  = o*tanh(c') = (1-ec)*rcp((1+eo)(1+ec)), ec = exp2(-2c'*log2e)
// 5 exp2 + 2 rcp per unit. Numerics verified (r3/r5: absmax 0.000488).
__device__ __forceinline__ float cell_update(float ai, float af, float ag,
                                             float ao, float& cst) {
    const float ei = __builtin_amdgcn_exp2f(-ai);
    const float ef = __builtin_amdgcn_exp2f(-af);
    const float eg = __builtin_amdgcn_exp2f(-ag);   // ag pre-scaled by 2log2e
    const float eo = __builtin_amdgcn_exp2f(-ao);
    const float p1  = (1.0f + ei) * (1.0f + eg);
    const float pf  = 1.0f + ef;
    const float num = fmaf(cst, p1, (1.0f - eg) * pf);
    const float cc  = num * __builtin_amdgcn_rcpf(p1 * pf);
    cst = cc;
    const float ec = __builtin_amdgcn_exp2f(cc * (-2.0f * LOG2E));  // true scale
    return (1.0f - ec) *
        __builtin_amdgcn_rcpf((1.0f + eo) * (1.0f + ec));      // o*tanh(c)
}

// Round 19: replace the LOAD-BEARING memory clobber with INDEX LAUNDERING.
// The r7-era clobber stops LICM from hoisting all A-frag/bsum1 ds_reads
// (448+64 regs -> spill), but as a FULL memory barrier it also forbids the
// scheduler from issuing iteration t+1's A-frag ds_reads under iteration
// t's ~800-cycle cell_update VALU tail -- exposed ds_read latency every
// iteration (the kernel is latency-bound: VALU 53%, MFMA 24%, LDS ~70%,
// no pipe saturated, TLP capped at 4 w/SIMD by block-size+LDS+regs).
// Fix: a zero-valued `ldsoff` laundered through asm("+v") each iteration,
// added to every wf/bsum1 index. LICM/GVN see a loop-variant address
// (hoist/CSE blocked -- same protection), but there is NO false memory
// dependence: wf/bsum1 are distinct LDS objects from state, so t+1 loads
// may interleave with t's tail. Real state deps (h0 write->read, gf WAR)
// are same-address and preserved by alias analysis.
// FAILURE SIGNATURE to watch: FETCH_SIZE >> 3.6 MB => LICM escaped =>
// restore the clobber form (pipe9) and declare.
//
// STRUCTURAL MODEL (rounds 0-5, all measured):
//  - DO NOT RE-ATTEMPT: r1 8-wave/32-batch A-reuse (218 us, latency-bound
//    at 2 w/SIMD); r2 xp-hoist (64 f32/lane -> scratch spill); r3 VALU
//    diet (kept, but neutral -- VALU not critical path); r4 SSTR=74
//    (breaks 16B alignment; conflicts are 2-way/structural/2.3%, leave);
//    r4 hand loop-rotation (regressed); r5 setprio on/off (neutral).
//    32x32 MFMA at 16 waves: needs 64 acc AGPR + ~76 persistent VGPR >
//    128-reg budget. At 8 waves: r1 regime. Blocked both ways.
//
// Merged steady-state body (one BB): L0(tt) + L1(tt-1). Per-wave LDS
// state machine: write h0(tt) -> read hf -> write h1(tt-1) -> read gf -> FC.
//
//   D[m=gate(256), n=batch(16)] = A[weights*scale] * B[z | h0 | x | h1]
// wf planes: 0=Wih0(z,K16; k=16 -> bias; rest 0) 1,2=Whh0 3,4=Wih1 5,6=Whh1.
// Gate order (PyTorch): 0=i,1=f,2=g,3=o ; g = 64*type + u, u=16a+4q+r;
// acc[ty] -> ty IS the gate type (mt = 4*ty+a).
__global__ __launch_bounds__(1024)
__attribute__((amdgpu_waves_per_eu(4, 4)))
void lstm2_pipe10(
        const float* __restrict__ z,
        const float* __restrict__ Wih0, const float* __restrict__ Whh0,
        const float* __restrict__ bih0, const float* __restrict__ bhh0,
        const float* __restrict__ Wih1, const float* __restrict__ Whh1,
        const float* __restrict__ bih1, const float* __restrict__ bhh1,
        const float* __restrict__ Wfc,  const float* __restrict__ bfc,
        float* __restrict__ out)
{
    __shared__ __align__(16) _Float16 wf[7 * 16 * 64 * 8];   // 114688 B
    __shared__ __align__(16) _Float16 wfcf[2 * 64 * 8];      //   2048 B
    __shared__ __align__(16) float    bsum1[256];            //   1024 B
    __shared__ __align__(16) _Float16 state[16][16 * 72];    //  36864 B
                                                             // 154624 B total

    const int tid  = threadIdx.x;
    const int wave = tid >> 6;           // 0..15
    const int lane = tid & 63;
    const int q    = lane >> 4;          // quad
    const int c    = lane & 15;          // batch col
    const int row0 = blockIdx.x * 256 + wave * 16;   // wave's batch base

    /* --- one-time staging: weights + biases, scaled (g rows by 2log2e) --- */
#pragma unroll 2
    for (int e = tid; e < 7 * 16 * 64 * 8; e += 1024) {
        const int j  = e & 7;
        const int lm = (e >> 3) & 63;
        const int mt = (e >> 9) & 15;
        const int p  = e >> 13;                  // fragment plane 0..6
        const int g  = mt * 16 + (lm & 15);      // gate row 0..255
        const int kk = (lm >> 4) * 8 + j;        // k within 32-chunk
        float v;
        if (p == 0)      v = (kk < LAT) ? Wih0[g * LAT + kk]
                           : (kk == LAT ? bih0[g] + bhh0[g] : 0.0f);
        else if (p == 1) v = Whh0[g * HID + kk];
        else if (p == 2) v = Whh0[g * HID + 32 + kk];
        else if (p == 3) v = Wih1[g * HID + kk];
        else if (p == 4) v = Wih1[g * HID + 32 + kk];
        else if (p == 5) v = Whh1[g * HID + kk];
        else             v = Whh1[g * HID + 32 + kk];
        const float sc = ((g >> 6) == 2) ? (2.0f * LOG2E) : LOG2E;
        wf[e] = (_Float16)(v * sc);
    }
    // FC A-fragments: row m=0 carries Wfc (TRUE scale), rows 1..15 zero
    if (tid < 2 * 64 * 8) {
        const int e  = tid;
        const int j  = e & 7;
        const int lm = (e >> 3) & 63;
        const int kc = e >> 9;
        const int kk = kc * 32 + (lm >> 4) * 8 + j;
        wfcf[e] = ((lm & 15) == 0) ? (_Float16)Wfc[kk] : (_Float16)0.0f;
    }
    if (tid < 256)
        bsum1[tid] = (bih1[tid] + bhh1[tid]) *
                     (((tid >> 6) == 2) ? (2.0f * LOG2E) : LOG2E);
    __syncthreads();   // the only barrier in the kernel

    _Float16* stW = &state[wave][0];
    const float bfcv = bfc[0];

    // FC fragments hoisted (SSA regs, never re-read)
    const v8h wfc0 = *(const v8h*)&wfcf[(0 * 64 + lane) * 8];
    const v8h wfc1 = *(const v8h*)&wfcf[(1 * 64 + lane) * 8];

    // z B-fragment (constant over t); element k=16 = 1.0 multiplies the
    // (scaled) bias column staged in plane 0.
    v8h zfrag = vzero8();
    if (q < 2) {
        const float* zp = z + (size_t)(row0 + c) * LAT + q * 8;
        const float4 za = *(const float4*)(zp);
        const float4 zb = *(const float4*)(zp + 4);
        zfrag[0] = (_Float16)za.x; zfrag[1] = (_Float16)za.y;
        zfrag[2] = (_Float16)za.z; zfrag[3] = (_Float16)za.w;
        zfrag[4] = (_Float16)zb.x; zfrag[5] = (_Float16)zb.y;
        zfrag[6] = (_Float16)zb.z; zfrag[7] = (_Float16)zb.w;
    }
    if (q == 2) zfrag[0] = (_Float16)1.0f;   // bias slot

    v8h hf0 = vzero8(), hf1 = vzero8();   // h0/x B-frags (k-halves)
    v8h gf0 = vzero8(), gf1 = vzero8();   // h1 B-frags
    v4h h1pk[4];                          // packed h1 awaiting deferred write
    float c0s[16], c1s[16];
#pragma unroll
    for (int i = 0; i < 16; ++i) { c0s[i] = 0.0f; c1s[i] = 0.0f; }

    // Laundered zero index: loop-variant to the compiler, 0 at runtime.
    unsigned ldsoff = 0;

#define AFRAG(pl, mt) \
    (*(const v8h*)&wf[ldsoff + (((pl) * 16 + (mt)) * 64 + lane) * 8])
#define MFMA16(A, B, C) __builtin_amdgcn_mfma_f32_16x16x32_f16((A), (B), (C), 0, 0, 0)

    auto l0_part = [&]() {   // L0 MFMAs + epilogue + h0 stores (uses old hf)
#pragma unroll
        for (int a = 0; a < 4; ++a) {
            v4f acc0[4];
#pragma unroll
            for (int ty = 0; ty < 4; ++ty) {
                const int mt = 4 * ty + a;
                v4f t0 = {0.f, 0.f, 0.f, 0.f};
                t0 = MFMA16(AFRAG(0, mt), zfrag, t0);
                t0 = MFMA16(AFRAG(1, mt), hf0,   t0);
                t0 = MFMA16(AFRAG(2, mt), hf1,   t0);
                acc0[ty] = t0;
            }
            float hh[4];
#pragma unroll
            for (int r = 0; r < 4; ++r)
                hh[r] = cell_update(acc0[0][r], acc0[1][r], acc0[2][r],
                                    acc0[3][r], c0s[a * 4 + r]);
            *(v4h*)&stW[c * 72 + 16 * a + 4 * q] = pack4(hh[0], hh[1], hh[2], hh[3]);
        }
    };

    auto l1_part = [&]() {   // L1 MFMAs + epilogue -> h1pk (uses old hf, gf)
#pragma unroll
        for (int a = 0; a < 4; ++a) {
            v4f acc1[4];
#pragma unroll
            for (int ty = 0; ty < 4; ++ty) {
                const int mt = 4 * ty + a;
                v4f t0 = *(const v4f*)&bsum1[ldsoff + 64 * ty + 16 * a + 4 * q];
                t0 = MFMA16(AFRAG(3, mt), hf0, t0);
                t0 = MFMA16(AFRAG(4, mt), hf1, t0);
                t0 = MFMA16(AFRAG(5, mt), gf0, t0);
                t0 = MFMA16(AFRAG(6, mt), gf1, t0);
                acc1[ty] = t0;
            }
            float hh[4];
#pragma unroll
            for (int r = 0; r < 4; ++r)
                hh[r] = cell_update(acc1[0][r], acc1[1][r], acc1[2][r],
                                    acc1[3][r], c1s[a * 4 + r]);
            h1pk[a] = pack4(hh[0], hh[1], hh[2], hh[3]);
        }
    };

    auto l0_finish = [&]() {   // pull new h0 into B-frag registers
        hf0 = *(const v8h*)&stW[c * 72 + 8 * q];
        hf1 = *(const v8h*)&stW[c * 72 + 32 + 8 * q];
    };

    auto l1_finish = [&](int trow) {   // h1 store, gf reload, FC, out
#pragma unroll
        for (int a = 0; a < 4; ++a)
            *(v4h*)&stW[c * 72 + 16 * a + 4 * q] = h1pk[a];
        gf0 = *(const v8h*)&stW[c * 72 + 8 * q];
        gf1 = *(const v8h*)&stW[c * 72 + 32 + 8 * q];
        v4f f = {0.f, 0.f, 0.f, 0.f};
        f = MFMA16(wfc0, gf0, f);
        f = MFMA16(wfc1, gf1, f);
        if (lane < 16)
            out[(size_t)(row0 + lane) * TSTEPS + trow] = f[0] + bfcv;
    };

    /* --------------------------- pipeline --------------------------- */
    l0_part();          // L0 step 0 (hf, gf are zero; ldsoff = const 0 here)
    l0_finish();

#pragma unroll 1
    for (int tt = 1; tt < TSTEPS; ++tt) {
        // Launder ldsoff: blocks LICM/CSE of wf/bsum1 reads (same protection
        // as the old memory clobber) WITHOUT a false memory dependence, so
        // the scheduler may overlap this iteration's ds_reads with the
        // previous iteration's VALU tail. Emits no instructions.
        __asm__ __volatile__("" : "+v"(ldsoff));
        l0_part();           // writes h0(tt) to stW
        l1_part();           // -> h1pk (registers only)
        l0_finish();         // hf <- h0(tt)
        l1_finish(tt - 1);   // h1 store, gf <- h1(tt-1), FC, out row tt-1
    }

    __asm__ __volatile__("" : "+v"(ldsoff));   // bar CSE into the epilogue
    l1_part();          // L1 step 14
    l1_finish(TSTEPS - 1);

#undef AFRAG
#undef MFMA16
}

extern "C" void kernel_launch(void* const* d_in, const int* in_sizes, int n_in,
                              void* d_out, int out_size, void* d_ws, size_t ws_size,
                              hipStream_t stream)
{
    (void)in_sizes; (void)n_in; (void)out_size; (void)d_ws; (void)ws_size;

    const float* z    = (const float*)d_in[0];
    const float* Wih0 = (const float*)d_in[1];
    const float* Whh0 = (const float*)d_in[2];
    const float* bih0 = (const float*)d_in[3];
    const float* bhh0 = (const float*)d_in[4];
    const float* Wih1 = (const float*)d_in[5];
    const float* Whh1 = (const float*)d_in[6];
    const float* bih1 = (const float*)d_in[7];
    const float* bhh1 = (const float*)d_in[8];
    const float* Wfc  = (const float*)d_in[9];
    const float* bfc  = (const float*)d_in[10];

    lstm2_pipe10<<<dim3(NBATCH / 256), dim3(1024), 0, stream>>>(
        z, Wih0, Whh0, bih0, bhh0, Wih1, Whh1, bih1, bhh1, Wfc, bfc,
        (float*)d_out);
}